// Round 1
// baseline (3359.456 us; speedup 1.0000x reference)
//
#include <hip/hip_runtime.h>
#include <hip/hip_bf16.h>

// Problem constants
#define N_NODES 2048
#define EMB 16
#define NB 16          // batch
#define NT 12          // time
#define BT 192         // NB*NT
#define D 64
#define C_COLS (BT * D)        // 12288 columns of the big GEMMs
#define TD (NT * D)            // 768 = per-(b,node) row length in x
#define BSTRIDE (N_NODES * TD) // 1572864 = per-b stride in x

typedef unsigned short ushort_t;

__device__ __forceinline__ float bf2f(__hip_bfloat16 v) { return __bfloat162float(v); }
__device__ __forceinline__ __hip_bfloat16 f2bf(float f) { return __float2bfloat16(f); }

// ---------------------------------------------------------------------------
// Kernel 1: S[n][m] = softmax_m( relu( E[n]·E[m] ) )   (one block per row n)
// ---------------------------------------------------------------------------
__global__ void supports_kernel(const float* __restrict__ E, float* __restrict__ S)
{
    __shared__ float en[EMB];
    __shared__ float red[256];
    const int n = blockIdx.x;
    const int tid = threadIdx.x;
    if (tid < EMB) en[tid] = E[n * EMB + tid];
    __syncthreads();

    float v[8];
    float mx = 0.0f; // relu output is >= 0
    #pragma unroll
    for (int j = 0; j < 8; ++j) {
        const int m = tid + j * 256;
        const float* em = E + m * EMB;
        float acc = 0.f;
        #pragma unroll
        for (int d = 0; d < EMB; ++d) acc += en[d] * em[d];
        acc = fmaxf(acc, 0.f);
        v[j] = acc;
        mx = fmaxf(mx, acc);
    }
    red[tid] = mx;
    __syncthreads();
    for (int s = 128; s > 0; s >>= 1) {
        if (tid < s) red[tid] = fmaxf(red[tid], red[tid + s]);
        __syncthreads();
    }
    mx = red[0];
    __syncthreads();

    float sum = 0.f;
    #pragma unroll
    for (int j = 0; j < 8; ++j) {
        v[j] = __expf(v[j] - mx);
        sum += v[j];
    }
    red[tid] = sum;
    __syncthreads();
    for (int s = 128; s > 0; s >>= 1) {
        if (tid < s) red[tid] += red[tid + s];
        __syncthreads();
    }
    const float inv = 1.f / red[0];
    #pragma unroll
    for (int j = 0; j < 8; ++j)
        S[(size_t)n * N_NODES + tid + j * 256] = v[j] * inv;
}

// ---------------------------------------------------------------------------
// Kernel 2/3: 64x64x16-tiled fp32 GEMM over nodes.
//   MODE 0:  Y1[n][c] = sum_m S[n][m] * X[m][c]          (X read from x, strided)
//   MODE 1:  Y2[n][c] = 2*sum_m S[n][m] * Y1[m][c] - X[n][c]
// X[m][c] with c = (b*NT+t)*D + d  ->  x[b*BSTRIDE + m*TD + (c % TD)]
// Output stored bf16.
// ---------------------------------------------------------------------------
template <int MODE>
__launch_bounds__(256, 4)
__global__ void gemm64_kernel(const float* __restrict__ S,
                              const float* __restrict__ x,
                              const __hip_bfloat16* __restrict__ Bsrc,
                              __hip_bfloat16* __restrict__ Out)
{
    __shared__ float As[16][65]; // [k][m], padded
    __shared__ float Bs[16][64]; // [k][c]

    const int tid = threadIdx.x;
    const int m0 = blockIdx.y * 64;
    const int c0 = blockIdx.x * 64;

    const int a_m = tid >> 2;        // 0..63
    const int a_k = (tid & 3) * 4;   // 0,4,8,12
    const int b_k = tid >> 4;        // 0..15
    const int b_c = (tid & 15) * 4;  // 0..60

    const int tm = (tid >> 4) * 4;   // 4-row group
    const int tn = (tid & 15) * 4;   // 4-col group

    float acc[4][4] = {};

    #pragma unroll 1
    for (int k0 = 0; k0 < N_NODES; k0 += 16) {
        // stage A (S tile)
        const float4 av = *reinterpret_cast<const float4*>(
            S + (size_t)(m0 + a_m) * N_NODES + k0 + a_k);
        // stage B
        float4 bv;
        if (MODE == 0) {
            const int c = c0 + b_c;
            const int b = c / TD;
            const int r = c - b * TD;
            bv = *reinterpret_cast<const float4*>(
                x + (size_t)b * BSTRIDE + (size_t)(k0 + b_k) * TD + r);
        } else {
            const ushort4 u = *reinterpret_cast<const ushort4*>(
                reinterpret_cast<const ushort_t*>(Bsrc) +
                (size_t)(k0 + b_k) * C_COLS + c0 + b_c);
            bv.x = __uint_as_float(((unsigned)u.x) << 16);
            bv.y = __uint_as_float(((unsigned)u.y) << 16);
            bv.z = __uint_as_float(((unsigned)u.z) << 16);
            bv.w = __uint_as_float(((unsigned)u.w) << 16);
        }
        __syncthreads(); // previous iter's compute reads done before overwrite
        As[a_k + 0][a_m] = av.x;
        As[a_k + 1][a_m] = av.y;
        As[a_k + 2][a_m] = av.z;
        As[a_k + 3][a_m] = av.w;
        *reinterpret_cast<float4*>(&Bs[b_k][b_c]) = bv;
        __syncthreads();

        #pragma unroll
        for (int kk = 0; kk < 16; ++kk) {
            const float a0 = As[kk][tm + 0];
            const float a1 = As[kk][tm + 1];
            const float a2 = As[kk][tm + 2];
            const float a3 = As[kk][tm + 3];
            const float4 b4 = *reinterpret_cast<const float4*>(&Bs[kk][tn]);
            acc[0][0] = fmaf(a0, b4.x, acc[0][0]);
            acc[0][1] = fmaf(a0, b4.y, acc[0][1]);
            acc[0][2] = fmaf(a0, b4.z, acc[0][2]);
            acc[0][3] = fmaf(a0, b4.w, acc[0][3]);
            acc[1][0] = fmaf(a1, b4.x, acc[1][0]);
            acc[1][1] = fmaf(a1, b4.y, acc[1][1]);
            acc[1][2] = fmaf(a1, b4.z, acc[1][2]);
            acc[1][3] = fmaf(a1, b4.w, acc[1][3]);
            acc[2][0] = fmaf(a2, b4.x, acc[2][0]);
            acc[2][1] = fmaf(a2, b4.y, acc[2][1]);
            acc[2][2] = fmaf(a2, b4.z, acc[2][2]);
            acc[2][3] = fmaf(a2, b4.w, acc[2][3]);
            acc[3][0] = fmaf(a3, b4.x, acc[3][0]);
            acc[3][1] = fmaf(a3, b4.y, acc[3][1]);
            acc[3][2] = fmaf(a3, b4.z, acc[3][2]);
            acc[3][3] = fmaf(a3, b4.w, acc[3][3]);
        }
    }

    // epilogue
    #pragma unroll
    for (int i = 0; i < 4; ++i) {
        const int row = m0 + tm + i;
        #pragma unroll
        for (int j = 0; j < 4; ++j) {
            float r = acc[i][j];
            const int c = c0 + tn + j;
            if (MODE == 1) {
                const int b = c / TD;
                const int rr = c - b * TD;
                r = 2.f * r - x[(size_t)b * BSTRIDE + (size_t)row * TD + rr];
            }
            Out[(size_t)row * C_COLS + c] = f2bf(r);
        }
    }
}

// ---------------------------------------------------------------------------
// Kernel 4: per-node gconv. One block per node n.
//   W[k][i][o] = sum_d E[n][d] * Wp[d][k][i][o]   (hypernetwork, in LDS)
//   bias[o]    = sum_d E[n][d] * Bp[d][o]
//   out[b,n,t,o] = bias[o] + sum_{k,i} G_k[bt][i] * W[k][i][o]
//   where G_0 = X row-n, G_1 = Y1 row-n, G_2 = Y2 row-n.
// ---------------------------------------------------------------------------
__launch_bounds__(256, 2)
__global__ void gconv_kernel(const float* __restrict__ x,
                             const float* __restrict__ E,
                             const float* __restrict__ Wp,
                             const float* __restrict__ Bp,
                             const __hip_bfloat16* __restrict__ Y1,
                             const __hip_bfloat16* __restrict__ Y2,
                             float* __restrict__ Out)
{
    __shared__ float Wl[3 * 64 * 64]; // 48 KB: W[k][i][o]
    __shared__ float Gl[3][16][64];   // 12 KB: 16-row chunk of the 3 sources
    __shared__ float bias[64];
    __shared__ float en[EMB];

    const int n = blockIdx.x;
    const int tid = threadIdx.x;

    if (tid < EMB) en[tid] = E[n * EMB + tid];
    __syncthreads();

    #pragma unroll 2
    for (int j = 0; j < 48; ++j) { // 12288 / 256
        const int f = j * 256 + tid;
        float a = 0.f;
        #pragma unroll
        for (int d = 0; d < EMB; ++d) a = fmaf(en[d], Wp[d * 12288 + f], a);
        Wl[f] = a;
    }
    if (tid < 64) {
        float a = 0.f;
        #pragma unroll
        for (int d = 0; d < EMB; ++d) a = fmaf(en[d], Bp[d * 64 + tid], a);
        bias[tid] = a;
    }

    const int o = tid & 63;
    const int rs4 = (tid >> 6) * 4; // this thread's 4-row group within a chunk

    #pragma unroll 1
    for (int chunk = 0; chunk < 12; ++chunk) {
        __syncthreads(); // previous chunk compute done (also covers Wl/bias at chunk 0)
        #pragma unroll
        for (int j = 0; j < 4; ++j) {
            const int e = j * 256 + tid;
            const int r = e >> 6;
            const int i = e & 63;
            const int bt = chunk * 16 + r;
            const int b = bt / NT;
            const int rr = (bt - b * NT) * 64 + i;
            Gl[0][r][i] = x[(size_t)b * BSTRIDE + (size_t)n * TD + rr];
            const size_t yc = (size_t)n * C_COLS + (size_t)bt * 64 + i;
            Gl[1][r][i] = bf2f(Y1[yc]);
            Gl[2][r][i] = bf2f(Y2[yc]);
        }
        __syncthreads();

        float acc[4];
        #pragma unroll
        for (int q = 0; q < 4; ++q) acc[q] = bias[o];

        #pragma unroll 1
        for (int k = 0; k < 3; ++k) {
            const float* Wk = Wl + k * 4096 + o;
            #pragma unroll
            for (int i = 0; i < 64; i += 4) {
                const float w0 = Wk[(i + 0) * 64];
                const float w1 = Wk[(i + 1) * 64];
                const float w2 = Wk[(i + 2) * 64];
                const float w3 = Wk[(i + 3) * 64];
                #pragma unroll
                for (int q = 0; q < 4; ++q) {
                    const float4 g = *reinterpret_cast<const float4*>(&Gl[k][rs4 + q][i]);
                    acc[q] = fmaf(g.x, w0, fmaf(g.y, w1, fmaf(g.z, w2, fmaf(g.w, w3, acc[q]))));
                }
            }
        }

        #pragma unroll
        for (int q = 0; q < 4; ++q) {
            const int bt = chunk * 16 + rs4 + q;
            const int b = bt / NT;
            const int t = bt - b * NT;
            Out[(((size_t)(b * N_NODES + n)) * NT + t) * 64 + o] = acc[q];
        }
    }
}

// ---------------------------------------------------------------------------
// Workspace layout (112 MB total):
//   [0, 16 MB)       S   fp32  2048x2048
//   [16 MB, 64 MB)   Y1  bf16  2048x12288
//   [64 MB, 112 MB)  Y2  bf16  2048x12288
// ---------------------------------------------------------------------------
extern "C" void kernel_launch(void* const* d_in, const int* in_sizes, int n_in,
                              void* d_out, int out_size, void* d_ws, size_t ws_size,
                              hipStream_t stream)
{
    const float* x  = (const float*)d_in[0];
    const float* E  = (const float*)d_in[1];
    const float* Wp = (const float*)d_in[2];
    const float* Bp = (const float*)d_in[3];
    float* Out = (float*)d_out;

    float* S = (float*)d_ws;
    __hip_bfloat16* Y1 = (__hip_bfloat16*)((char*)d_ws + (size_t)16 * 1024 * 1024);
    __hip_bfloat16* Y2 = (__hip_bfloat16*)((char*)d_ws + (size_t)64 * 1024 * 1024);

    supports_kernel<<<N_NODES, 256, 0, stream>>>(E, S);

    dim3 gg(C_COLS / 64, N_NODES / 64); // (192, 32)
    gemm64_kernel<0><<<gg, 256, 0, stream>>>(S, x, nullptr, Y1);
    gemm64_kernel<1><<<gg, 256, 0, stream>>>(S, x, Y1, Y2);

    gconv_kernel<<<N_NODES, 256, 0, stream>>>(x, E, Wp, Bp, Y1, Y2, Out);
}

// Round 2
// 820.768 us; speedup vs baseline: 4.0931x; 4.0931x over previous
//
#include <hip/hip_runtime.h>
#include <hip/hip_bf16.h>

// Problem constants
#define N_NODES 2048
#define EMB 16
#define NT 12
#define BT 192
#define C_COLS 12288           // BT*64
#define TD 768                 // NT*64, per-(b,node) row length in x
#define BSTRIDE (N_NODES * TD) // per-b stride in x
#define KDIM 2048              // contraction dim (nodes)

typedef unsigned short u16;
typedef unsigned int u32;
typedef __attribute__((ext_vector_type(8))) __bf16 bf16x8;
typedef __attribute__((ext_vector_type(4))) float f32x4;

__device__ __forceinline__ u16 f2bfu(float f) { // RNE fp32 -> bf16 bits
    u32 u = __float_as_uint(f);
    return (u16)((u + 0x7FFFu + ((u >> 16) & 1u)) >> 16);
}
__device__ __forceinline__ float bfu2f(u16 h) {
    return __uint_as_float(((u32)h) << 16);
}

// async 16B global->LDS (lds dest = wave-uniform base + lane*16)
__device__ __forceinline__ void gl2lds16(const void* g, void* l) {
    __builtin_amdgcn_global_load_lds(
        (const __attribute__((address_space(1))) u32*)g,
        (__attribute__((address_space(3))) u32*)l, 16, 0, 0);
}

// ---------------------------------------------------------------------------
// Kernel 1: Sb[n][m] = bf16( softmax_m( relu( E[n]·E[m] ) ) )
// ---------------------------------------------------------------------------
__global__ void supports_kernel(const float* __restrict__ E, u16* __restrict__ Sb)
{
    __shared__ float en[EMB];
    __shared__ float red[256];
    const int n = blockIdx.x;
    const int tid = threadIdx.x;
    if (tid < EMB) en[tid] = E[n * EMB + tid];
    __syncthreads();

    float v[8];
    float mx = 0.0f; // relu >= 0
    #pragma unroll
    for (int j = 0; j < 8; ++j) {
        const int m = tid + j * 256;
        const float* em = E + m * EMB;
        float acc = 0.f;
        #pragma unroll
        for (int d = 0; d < EMB; ++d) acc += en[d] * em[d];
        acc = fmaxf(acc, 0.f);
        v[j] = acc;
        mx = fmaxf(mx, acc);
    }
    red[tid] = mx;
    __syncthreads();
    for (int s = 128; s > 0; s >>= 1) {
        if (tid < s) red[tid] = fmaxf(red[tid], red[tid + s]);
        __syncthreads();
    }
    mx = red[0];
    __syncthreads();

    float sum = 0.f;
    #pragma unroll
    for (int j = 0; j < 8; ++j) { v[j] = __expf(v[j] - mx); sum += v[j]; }
    red[tid] = sum;
    __syncthreads();
    for (int s = 128; s > 0; s >>= 1) {
        if (tid < s) red[tid] += red[tid + s];
        __syncthreads();
    }
    const float inv = 1.f / red[0];
    #pragma unroll
    for (int j = 0; j < 8; ++j)
        Sb[(size_t)n * KDIM + tid + j * 256] = f2bfu(v[j] * inv);
}

// ---------------------------------------------------------------------------
// Kernel 2: xcast — XbT[c_local][m] = bf16(x[b][m][r]),  c = c0g + c_local,
// b = c/768, r = c%768. 64x64 LDS-tiled transpose, coalesced both sides.
// ---------------------------------------------------------------------------
__global__ void xcast_kernel(const float* __restrict__ x, u16* __restrict__ XbT, int c0g)
{
    __shared__ u16 tile[64][65];
    const int tid = threadIdx.x;
    const int cg = c0g + blockIdx.x * 64;  // global c base (64 | 768 so no b-straddle)
    const int b = cg / TD;
    const int r0 = cg - b * TD;
    const int m0 = blockIdx.y * 64;
    const float* xp = x + (size_t)b * BSTRIDE + (size_t)m0 * TD + r0;

    const int lc = tid & 63;
    const int rg = tid >> 6; // 0..3
    #pragma unroll
    for (int j = 0; j < 16; ++j) {
        const int mr = j * 4 + rg;
        tile[lc][mr] = f2bfu(xp[(size_t)mr * TD + lc]);
    }
    __syncthreads();
    u16* op = XbT + (size_t)(blockIdx.x * 64) * KDIM + m0;
    #pragma unroll
    for (int j = 0; j < 16; ++j) {
        const int cr = j * 4 + rg;
        op[(size_t)cr * KDIM + lc] = tile[cr][lc];
    }
}

// ---------------------------------------------------------------------------
// Kernel 3: bf16 MFMA GEMM, 128x128 tile, BK=32, 4 waves (2x2 of 64x64).
//   Out[m][c] = sum_k A[m][k] * B[c][k]   (B given k-contiguous / transposed)
//   MODE 0: A=Sb, B=XbT_c   -> Y1T_c[c][m] (ushort4) + Y1row[m][c0g+c] (scalar)
//   MODE 1: A=Sb, B=Y1T_c   -> Y2row[m][c0g+c] = 2*acc - XbT_c[c][m]
// ---------------------------------------------------------------------------
template <int MODE>
__launch_bounds__(256, 3)
__global__ void mfma_gemm(const u16* __restrict__ A,
                          const u16* __restrict__ B,
                          u16* __restrict__ OutT,
                          u16* __restrict__ OutRow,
                          const u16* __restrict__ Xc,
                          int c0g)
{
    __shared__ char smem[16384];
    char* As = smem;          // [128 m-rows][32 k] bf16, row = 64 B
    char* Bs = smem + 8192;   // [128 c-rows][32 k] bf16

    const int tid = threadIdx.x;
    const int lane = tid & 63;
    const int w = tid >> 6;
    const int wm = w >> 1, wn = w & 1;
    const int ln15 = lane & 15, quad = lane >> 4;

    const int m0 = blockIdx.y * 128;
    const int cb = blockIdx.x * 128; // chunk-local c base

    // staging: 8 A-issues + 8 B-issues of 16 rows x 16 B; wave w does 2 of each
    const int q0 = 2 * w, q1 = 2 * w + 1;
    const int srow = lane >> 2;       // 0..15 row within issue
    const int skol = (lane & 3) * 8;  // k element offset (16 B)
    const u16* ga0 = A + (size_t)(m0 + q0 * 16 + srow) * KDIM + skol;
    const u16* ga1 = A + (size_t)(m0 + q1 * 16 + srow) * KDIM + skol;
    const u16* gb0 = B + (size_t)(cb + q0 * 16 + srow) * KDIM + skol;
    const u16* gb1 = B + (size_t)(cb + q1 * 16 + srow) * KDIM + skol;
    char* la0 = As + q0 * 1024;
    char* la1 = As + q1 * 1024;
    char* lb0 = Bs + q0 * 1024;
    char* lb1 = Bs + q1 * 1024;

    f32x4 acc[4][4] = {};

    for (int k0 = 0; k0 < KDIM; k0 += 32) {
        __syncthreads();            // prior compute done reading LDS
        gl2lds16(ga0, la0);
        gl2lds16(ga1, la1);
        gl2lds16(gb0, lb0);
        gl2lds16(gb1, lb1);
        ga0 += 32; ga1 += 32; gb0 += 32; gb1 += 32;
        __syncthreads();            // drains vmcnt: tiles resident

        bf16x8 af[4], bg[4];
        #pragma unroll
        for (int i = 0; i < 4; ++i) {
            af[i] = *(const bf16x8*)(As + ((wm * 64 + i * 16 + ln15) * 64 + quad * 16));
            bg[i] = *(const bf16x8*)(Bs + ((wn * 64 + i * 16 + ln15) * 64 + quad * 16));
        }
        #pragma unroll
        for (int mi = 0; mi < 4; ++mi)
            #pragma unroll
            for (int ni = 0; ni < 4; ++ni)
                acc[mi][ni] = __builtin_amdgcn_mfma_f32_16x16x32_bf16(
                    af[mi], bg[ni], acc[mi][ni], 0, 0, 0);
    }

    // epilogue: C/D layout col = lane&15, row = quad*4 + reg
    const int mbase = m0 + wm * 64 + quad * 4;
    const int cbase = cb + wn * 64 + ln15;
    #pragma unroll
    for (int mi = 0; mi < 4; ++mi) {
        #pragma unroll
        for (int ni = 0; ni < 4; ++ni) {
            const f32x4 v = acc[mi][ni];
            const int mm = mbase + mi * 16;
            const int cc = cbase + ni * 16;
            if (MODE == 0) {
                ushort4 u;
                u.x = f2bfu(v.x); u.y = f2bfu(v.y); u.z = f2bfu(v.z); u.w = f2bfu(v.w);
                *(ushort4*)(OutT + (size_t)cc * KDIM + mm) = u;
                u16* orow = OutRow + (size_t)mm * C_COLS + c0g + cc;
                orow[0 * C_COLS] = u.x;
                orow[1 * C_COLS] = u.y;
                orow[2 * C_COLS] = u.z;
                orow[3 * C_COLS] = u.w;
            } else {
                const ushort4 xv = *(const ushort4*)(Xc + (size_t)cc * KDIM + mm);
                u16* orow = OutRow + (size_t)mm * C_COLS + c0g + cc;
                orow[0 * C_COLS] = f2bfu(2.f * v.x - bfu2f(xv.x));
                orow[1 * C_COLS] = f2bfu(2.f * v.y - bfu2f(xv.y));
                orow[2 * C_COLS] = f2bfu(2.f * v.z - bfu2f(xv.z));
                orow[3 * C_COLS] = f2bfu(2.f * v.w - bfu2f(xv.w));
            }
        }
    }
}

// ---------------------------------------------------------------------------
// Kernel 4: per-node gconv (unchanged structure from round 1)
// ---------------------------------------------------------------------------
__launch_bounds__(256, 2)
__global__ void gconv_kernel(const float* __restrict__ x,
                             const float* __restrict__ E,
                             const float* __restrict__ Wp,
                             const float* __restrict__ Bp,
                             const u16* __restrict__ Y1,
                             const u16* __restrict__ Y2,
                             float* __restrict__ Out)
{
    __shared__ float Wl[3 * 64 * 64];
    __shared__ float Gl[3][16][64];
    __shared__ float bias[64];
    __shared__ float en[EMB];

    const int n = blockIdx.x;
    const int tid = threadIdx.x;

    if (tid < EMB) en[tid] = E[n * EMB + tid];
    __syncthreads();

    #pragma unroll 2
    for (int j = 0; j < 48; ++j) {
        const int f = j * 256 + tid;
        float a = 0.f;
        #pragma unroll
        for (int d = 0; d < EMB; ++d) a = fmaf(en[d], Wp[d * 12288 + f], a);
        Wl[f] = a;
    }
    if (tid < 64) {
        float a = 0.f;
        #pragma unroll
        for (int d = 0; d < EMB; ++d) a = fmaf(en[d], Bp[d * 64 + tid], a);
        bias[tid] = a;
    }

    const int o = tid & 63;
    const int rs4 = (tid >> 6) * 4;

    #pragma unroll 1
    for (int chunk = 0; chunk < 12; ++chunk) {
        __syncthreads();
        #pragma unroll
        for (int j = 0; j < 4; ++j) {
            const int e = j * 256 + tid;
            const int r = e >> 6;
            const int i = e & 63;
            const int bt = chunk * 16 + r;
            const int b = bt / NT;
            const int rr = (bt - b * NT) * 64 + i;
            Gl[0][r][i] = x[(size_t)b * BSTRIDE + (size_t)n * TD + rr];
            const size_t yc = (size_t)n * C_COLS + (size_t)bt * 64 + i;
            Gl[1][r][i] = bfu2f(Y1[yc]);
            Gl[2][r][i] = bfu2f(Y2[yc]);
        }
        __syncthreads();

        float acc[4];
        #pragma unroll
        for (int q = 0; q < 4; ++q) acc[q] = bias[o];

        #pragma unroll 1
        for (int k = 0; k < 3; ++k) {
            const float* Wk = Wl + k * 4096 + o;
            #pragma unroll
            for (int i = 0; i < 64; i += 4) {
                const float w0 = Wk[(i + 0) * 64];
                const float w1 = Wk[(i + 1) * 64];
                const float w2 = Wk[(i + 2) * 64];
                const float w3 = Wk[(i + 3) * 64];
                #pragma unroll
                for (int q = 0; q < 4; ++q) {
                    const float4 g = *reinterpret_cast<const float4*>(&Gl[k][rs4 + q][i]);
                    acc[q] = fmaf(g.x, w0, fmaf(g.y, w1, fmaf(g.z, w2, fmaf(g.w, w3, acc[q]))));
                }
            }
        }

        #pragma unroll
        for (int q = 0; q < 4; ++q) {
            const int bt = chunk * 16 + rs4 + q;
            const int b = bt / NT;
            const int t = bt - b * NT;
            Out[(((size_t)(b * N_NODES + n)) * NT + t) * 64 + o] = acc[q];
        }
    }
}

// ---------------------------------------------------------------------------
// Workspace (parametric in ws_size; all paths do identical math):
//   Sb    @ 0     (8 MiB)   bf16 2048x2048
//   Y1row @ 8 M   (48 MiB)  bf16 2048x12288
//   Y2row @ 56 M  (48 MiB)  bf16 2048x12288
//   XbT_c @ 104 M (CW*2048*2) chunk B-operand
//   Y1T_c @ 104M + chunk    chunk Y1 transposed
// nc chosen smallest s.t. 104 MiB + 2*chunk fits ws_size (nc=12 -> 112 MiB,
// exactly the round-1-verified footprint).
// ---------------------------------------------------------------------------
extern "C" void kernel_launch(void* const* d_in, const int* in_sizes, int n_in,
                              void* d_out, int out_size, void* d_ws, size_t ws_size,
                              hipStream_t stream)
{
    const float* x  = (const float*)d_in[0];
    const float* E  = (const float*)d_in[1];
    const float* Wp = (const float*)d_in[2];
    const float* Bp = (const float*)d_in[3];
    float* Out = (float*)d_out;

    const size_t MiB = 1024 * 1024;
    u16* Sb    = (u16*)d_ws;
    u16* Y1row = (u16*)((char*)d_ws + 8 * MiB);
    u16* Y2row = (u16*)((char*)d_ws + 56 * MiB);
    char* chunkbase = (char*)d_ws + 104 * MiB;

    const int cands[5] = {1, 2, 3, 6, 12};
    int nc = 12;
    for (int i = 0; i < 5; ++i) {
        const size_t chunk_bytes = (size_t)(C_COLS / cands[i]) * KDIM * 2;
        if (104 * MiB + 2 * chunk_bytes <= ws_size) { nc = cands[i]; break; }
    }
    const int CW = C_COLS / nc;
    u16* XbTc = (u16*)chunkbase;
    u16* Y1Tc = (u16*)(chunkbase + (size_t)CW * KDIM * 2);

    supports_kernel<<<N_NODES, 256, 0, stream>>>(E, Sb);

    for (int c = 0; c < nc; ++c) {
        const int c0g = c * CW;
        xcast_kernel<<<dim3(CW / 64, 32), 256, 0, stream>>>(x, XbTc, c0g);
        mfma_gemm<0><<<dim3(CW / 128, 16), 256, 0, stream>>>(Sb, XbTc, Y1Tc, Y1row, nullptr, c0g);
        mfma_gemm<1><<<dim3(CW / 128, 16), 256, 0, stream>>>(Sb, Y1Tc, nullptr, Y2row, XbTc, c0g);
    }

    gconv_kernel<<<N_NODES, 256, 0, stream>>>(x, E, Wp, Bp, Y1row, Y2row, Out);
}